// Round 1
// 346.258 us; speedup vs baseline: 1.0513x; 1.0513x over previous
//
#include <hip/hip_runtime.h>

// SparseMeshConv fused kernel, R3 (MI355X / gfx950)
//   patch = [x, |a-c|, a+c, |b-d|, b+d]  (a=x[idx1], b=x[idx2], c=x[idx3], d=x[idx4])
//   y = LN(patch @ W + bias) * gamma + beta + x;  out = gelu_erf(y)
// R3 vs R2 (275 us fused dispatch, MfmaUtil 9.7 / VALU 21 / HBM 18% -> latency-bound):
//  - W no longer staged in LDS: waves read DISJOINT 64-col groups, so LDS W-staging
//    shared nothing. Wt is pre-laid-out in per-lane fragment order -> coalesced 16B
//    register loads from L2 (640 KB, L2-resident). LDS 40960 -> 8192 B.
//  - __syncthreads (vmcnt(0)+lgkmcnt(0) drain) replaced by raw s_barrier + lgkmcnt(0)
//    only. W fragments for chunk k+1 and gather loads now stay IN FLIGHT across the
//    barrier for a full iteration (compiler emits counted vmcnt before uses).
//    Issue order per iter: gathers(kn) first, then W(kn) -> waiting on gathers at
//    staging leaves the newer W loads outstanding.
//  - s_setprio(1) around the MFMA cluster (3 independent blocks/CU).

#define N_ROWS   100000
#define C        256
#define BK       32
#define NCHUNK   40      // 1280 / 32
#define BM       64
#define CHUNK_V  1024    // bf16x8 granules per K-chunk in Wt (4 wv * 4 ni * 64 lanes)
#define LN_EPS   1e-5f

typedef __bf16 bf16;
typedef bf16  bf16x8 __attribute__((ext_vector_type(8)));
typedef float f32x4  __attribute__((ext_vector_type(4)));

union BV  { bf16x8 v; bf16 h[8]; };
union FV2 { float4 q[2]; float f[8]; };

// barrier that does NOT drain vmcnt: LDS visibility only
#define LBAR() asm volatile("s_waitcnt lgkmcnt(0)\n\ts_barrier" ::: "memory")

// K-chunk -> original W row mapping (BK=32):
//  kc 0..7   : x slice            kRow = kc*32 + kk
//  kc 8..23  : u=kc-8             kRow = 256 + (u&1)*256 + (u>>1)*32 + kk   (|a-c| / a+c)
//  kc 24..39 : u=kc-24            kRow = 768 + (u&1)*256 + (u>>1)*32 + kk   (|b-d| / b+d)
// Wt layout = exact MFMA B-fragment order, one bf16x8 per (kc,wv,ni,lane):
//  Wt[((kc*4 + wv)*4 + ni)*64 + lane] .h[e] = W[kRow(kc, (lane>>4)*8+e)][wv*64+ni*16+(lane&15)]
__global__ void wprep(const float* __restrict__ W, bf16* __restrict__ Wt) {
    int t = blockIdx.x * 256 + threadIdx.x;
    if (t >= NCHUNK * 4 * 4 * 64) return;          // 40960 granules
    int lane = t & 63;
    int ni   = (t >> 6) & 3;
    int wv   = (t >> 8) & 3;
    int kc   = t >> 10;
    int l16  = lane & 15, quad = lane >> 4;
    int n = wv * 64 + ni * 16 + l16;
    int base;
    if (kc < 8)       base = kc * 32;
    else if (kc < 24) { int u = kc - 8;  base = 256 + (u & 1) * 256 + (u >> 1) * 32; }
    else              { int u = kc - 24; base = 768 + (u & 1) * 256 + (u >> 1) * 32; }
    BV o;
    #pragma unroll
    for (int e = 0; e < 8; ++e) {
        int kRow = base + quad * 8 + e;
        o.h[e] = (bf16)W[(size_t)kRow * C + n];
    }
    ((bf16x8*)Wt)[t] = o.v;
}

__global__ __launch_bounds__(256, 3)
void fused(const float* __restrict__ x,
           const int* __restrict__ idx1, const int* __restrict__ idx2,
           const int* __restrict__ idx3, const int* __restrict__ idx4,
           const bf16* __restrict__ Wt,
           const float* __restrict__ bias,
           const float* __restrict__ gamma_, const float* __restrict__ beta_,
           float* __restrict__ out)
{
    __shared__ __align__(16) union {
        bf16 a[2][BM * BK];                             // 8192 B, swizzled A tiles
        struct { float rsum[BM][4]; float rsq[BM][4]; float mu[BM]; float rs[BM]; } red;
    } SA;                                               // total LDS = 8192 B

    const int tid  = threadIdx.x;
    const int lane = tid & 63;
    const int wv   = tid >> 6;       // wave -> column group (wv*64)
    const int quad = lane >> 4;
    const int l16  = lane & 15;
    const int r0   = blockIdx.x * BM;

    const int r_st = tid >> 2;       // staging row 0..63
    const int q_st = tid & 3;        // 8-float eighth of the 32-col slice
    int gr_self = r0 + r_st; if (gr_self >= N_ROWS) gr_self = 0;
    const int ia = idx1[gr_self], ib = idx2[gr_self];
    const int ic = idx3[gr_self], id = idx4[gr_self];

    const int a_w_off = r_st * 32 + ((q_st ^ ((r_st >> 1) & 3)) << 3);
    int a_r_off[4];
    #pragma unroll
    for (int mi = 0; mi < 4; ++mi) {
        int m = mi * 16 + l16;
        a_r_off[mi] = m * 32 + ((quad ^ ((m >> 1) & 3)) << 3);
    }

    // per-lane W fragment pointer: Wq[kc*1024 + ni*64] is this lane's bf16x8
    const bf16x8* Wq = (const bf16x8*)Wt + wv * 256 + lane;

    f32x4 acc[4][4] = {};
    bf16x8 hold;                     // held (a+c)/(b+d) bf16 for odd pair chunk
    bf16x8 wf[4], wfn[4];

    // ---- prologue: stage chunk 0 (self slice 0); load W fragments for kc=0
    {
        const float4* p = (const float4*)(x + (size_t)gr_self * C + (q_st << 3));
        FV2 u; u.q[0] = p[0]; u.q[1] = p[1];
        #pragma unroll
        for (int j = 0; j < 4; ++j) wf[j] = Wq[j * 64];
        BV b0;
        #pragma unroll
        for (int j = 0; j < 8; ++j) b0.h[j] = (bf16)u.f[j];
        *(bf16x8*)&SA.a[0][a_w_off] = b0.v;
    }
    LBAR();

    for (int kc = 0; kc < NCHUNK; ++kc) {
        const int kn = kc + 1;

        // ---- issue gather/self loads for chunk kn (FIRST: oldest in vmem queue)
        FV2 la, lc;
        int mode = 0;        // 0 held/none, 1 self slice, 2 pair (diff now, sum held)
        if (kn < 8) {
            mode = 1;
            const float4* p = (const float4*)(x + (size_t)gr_self * C + (kn << 5) + (q_st << 3));
            la.q[0] = p[0]; la.q[1] = p[1];
        } else if (kn < NCHUNK) {
            int u = (kn < 24) ? (kn - 8) : (kn - 24);
            if (!(u & 1)) {
                mode = 2;
                int rA = (kn < 24) ? ia : ib;
                int rC = (kn < 24) ? ic : id;
                int off = ((u >> 1) << 5) + (q_st << 3);
                const float4* pa = (const float4*)(x + (size_t)rA * C + off);
                const float4* pc = (const float4*)(x + (size_t)rC * C + off);
                la.q[0] = pa[0]; la.q[1] = pa[1];
                lc.q[0] = pc[0]; lc.q[1] = pc[1];
            }
        }

        // ---- issue W fragment loads for chunk kn (stay in flight across barrier)
        if (kn < NCHUNK) {
            const bf16x8* wp = Wq + (size_t)kn * CHUNK_V;
            #pragma unroll
            for (int j = 0; j < 4; ++j) wfn[j] = wp[j * 64];
        }

        // ---- MFMA on A buffer kc&1 with in-register W fragments
        {
            const bf16* Ab = SA.a[kc & 1];
            bf16x8 af[4];
            #pragma unroll
            for (int mi = 0; mi < 4; ++mi)
                af[mi] = *(const bf16x8*)&Ab[a_r_off[mi]];
            __builtin_amdgcn_s_setprio(1);
            #pragma unroll
            for (int mi = 0; mi < 4; ++mi)
                #pragma unroll
                for (int ni = 0; ni < 4; ++ni)
                    acc[mi][ni] = __builtin_amdgcn_mfma_f32_16x16x32_bf16(
                        af[mi], wf[ni], acc[mi][ni], 0, 0, 0);
            __builtin_amdgcn_s_setprio(0);
        }

        // ---- convert + stage chunk kn into the other A buffer; rotate W regs
        if (kn < NCHUNK) {
            BV sv;
            if (mode == 1) {
                #pragma unroll
                for (int j = 0; j < 8; ++j) sv.h[j] = (bf16)la.f[j];
            } else if (mode == 2) {
                BV hs;
                #pragma unroll
                for (int j = 0; j < 8; ++j) {
                    sv.h[j] = (bf16)fabsf(la.f[j] - lc.f[j]);
                    hs.h[j] = (bf16)(la.f[j] + lc.f[j]);
                }
                hold = hs.v;
            } else {
                sv.v = hold;
            }
            *(bf16x8*)&SA.a[kn & 1][a_w_off] = sv.v;
            #pragma unroll
            for (int j = 0; j < 4; ++j) wf[j] = wfn[j];
            LBAR();   // lgkmcnt(0) + s_barrier only — vmcnt stays counted
        }
    }

    // ---- epilogue: +bias, LN stats, normalize, residual, exact GELU
    float bcol[4], gcol[4], ecol[4];
    #pragma unroll
    for (int ni = 0; ni < 4; ++ni) {
        int cidx = wv * 64 + ni * 16 + l16;
        bcol[ni] = bias[cidx]; gcol[ni] = gamma_[cidx]; ecol[ni] = beta_[cidx];
    }
    #pragma unroll
    for (int mi = 0; mi < 4; ++mi)
        #pragma unroll
        for (int ni = 0; ni < 4; ++ni)
            #pragma unroll
            for (int rg = 0; rg < 4; ++rg)
                acc[mi][ni][rg] += bcol[ni];

    #pragma unroll
    for (int mi = 0; mi < 4; ++mi) {
        #pragma unroll
        for (int rg = 0; rg < 4; ++rg) {
            float s = 0.f, q = 0.f;
            #pragma unroll
            for (int ni = 0; ni < 4; ++ni) {
                float y = acc[mi][ni][rg];
                s += y; q += y * y;
            }
            #pragma unroll
            for (int m = 1; m <= 8; m <<= 1) {
                s += __shfl_xor(s, m, 64);
                q += __shfl_xor(q, m, 64);
            }
            if (l16 == 0) {
                int row = mi * 16 + quad * 4 + rg;
                SA.red.rsum[row][wv] = s;
                SA.red.rsq [row][wv] = q;
            }
        }
    }
    __syncthreads();
    if (tid < BM) {
        float s  = SA.red.rsum[tid][0] + SA.red.rsum[tid][1] + SA.red.rsum[tid][2] + SA.red.rsum[tid][3];
        float q  = SA.red.rsq [tid][0] + SA.red.rsq [tid][1] + SA.red.rsq [tid][2] + SA.red.rsq [tid][3];
        float mu = s * (1.0f / C);
        float var = q * (1.0f / C) - mu * mu;
        SA.red.mu[tid] = mu;
        SA.red.rs[tid] = rsqrtf(var + LN_EPS);
    }
    __syncthreads();

    #pragma unroll
    for (int mi = 0; mi < 4; ++mi) {
        #pragma unroll
        for (int rg = 0; rg < 4; ++rg) {
            int row  = mi * 16 + quad * 4 + rg;
            int grow = r0 + row;
            if (grow >= N_ROWS) continue;
            float mu = SA.red.mu[row], rs = SA.red.rs[row];
            #pragma unroll
            for (int ni = 0; ni < 4; ++ni) {
                int cidx = wv * 64 + ni * 16 + l16;
                float y = (acc[mi][ni][rg] - mu) * rs * gcol[ni] + ecol[ni];
                y += x[(size_t)grow * C + cidx];
                float g = 0.5f * y * (1.0f + erff(y * 0.70710678118654752f));
                out[(size_t)grow * C + cidx] = g;
            }
        }
    }
}

extern "C" void kernel_launch(void* const* d_in, const int* in_sizes, int n_in,
                              void* d_out, int out_size, void* d_ws, size_t ws_size,
                              hipStream_t stream) {
    const float* x  = (const float*)d_in[0];
    const int*   i1 = (const int*)d_in[1];
    const int*   i2 = (const int*)d_in[2];
    const int*   i3 = (const int*)d_in[3];
    const int*   i4 = (const int*)d_in[4];
    const float* W  = (const float*)d_in[5];
    const float* b  = (const float*)d_in[6];
    const float* gm = (const float*)d_in[7];
    const float* bt = (const float*)d_in[8];
    float* outp = (float*)d_out;
    bf16* Wt = (bf16*)d_ws;   // 40*1024*16 = 640 KB, fragment-order bf16 W

    wprep<<<(NCHUNK * 4 * 4 * 64 + 255) / 256, 256, 0, stream>>>(W, Wt);
    fused<<<(N_ROWS + BM - 1) / BM, 256, 0, stream>>>(
        x, i1, i2, i3, i4, Wt, b, gm, bt, outp);
}

// Round 2
// 334.344 us; speedup vs baseline: 1.0887x; 1.0356x over previous
//
#include <hip/hip_runtime.h>

// SparseMeshConv fused kernel, R4 (MI355X / gfx950)
//   patch = [x, |a-c|, a+c, |b-d|, b+d]  (a=x[idx1], b=x[idx2], c=x[idx3], d=x[idx4])
//   y = LN(patch @ W + bias) * gamma + beta + x;  out = gelu_erf(y)
// R4 vs R3 (215 us, MfmaUtil 12.6 / VALU 27 / HBM 23.6% -> still latency-bound):
//  - Gather/self loads prefetched D=2 iterations ahead: loads for chunk kc+2 issued
//    at iteration kc; staging of chunk kc+1 consumes registers loaded a FULL
//    iteration earlier -> zero vmem wait on the stage path (R3 covered the gather
//    only with one MFMA block ~100 cyc vs >1000 cyc effective random-row latency).
//  - Main loop fully unrolled (40 iters): mode branches constant-fold, gather
//    addresses become base+imm, cur<-nxt rotation is pure register renaming.
//  - Everything else identical: W fragments as registers from L2-resident Wt,
//    lgkmcnt-only barrier (vmcnt stays counted across it), setprio around MFMA.

#define N_ROWS   100000
#define C        256
#define BK       32
#define NCHUNK   40      // 1280 / 32
#define BM       64
#define CHUNK_V  1024    // bf16x8 granules per K-chunk in Wt (4 wv * 4 ni * 64 lanes)
#define LN_EPS   1e-5f

typedef __bf16 bf16;
typedef bf16  bf16x8 __attribute__((ext_vector_type(8)));
typedef float f32x4  __attribute__((ext_vector_type(4)));

union BV  { bf16x8 v; bf16 h[8]; };
union FV2 { float4 q[2]; float f[8]; };

// barrier that does NOT drain vmcnt: LDS visibility only
#define LBAR() asm volatile("s_waitcnt lgkmcnt(0)\n\ts_barrier" ::: "memory")

// K-chunk -> original W row mapping (BK=32):
//  kc 0..7   : x slice            kRow = kc*32 + kk
//  kc 8..23  : u=kc-8             kRow = 256 + (u&1)*256 + (u>>1)*32 + kk   (|a-c| / a+c)
//  kc 24..39 : u=kc-24            kRow = 768 + (u&1)*256 + (u>>1)*32 + kk   (|b-d| / b+d)
// Wt layout = exact MFMA B-fragment order, one bf16x8 per (kc,wv,ni,lane):
//  Wt[((kc*4 + wv)*4 + ni)*64 + lane] .h[e] = W[kRow(kc, (lane>>4)*8+e)][wv*64+ni*16+(lane&15)]
__global__ void wprep(const float* __restrict__ W, bf16* __restrict__ Wt) {
    int t = blockIdx.x * 256 + threadIdx.x;
    if (t >= NCHUNK * 4 * 4 * 64) return;          // 40960 granules
    int lane = t & 63;
    int ni   = (t >> 6) & 3;
    int wv   = (t >> 8) & 3;
    int kc   = t >> 10;
    int l16  = lane & 15, quad = lane >> 4;
    int n = wv * 64 + ni * 16 + l16;
    int base;
    if (kc < 8)       base = kc * 32;
    else if (kc < 24) { int u = kc - 8;  base = 256 + (u & 1) * 256 + (u >> 1) * 32; }
    else              { int u = kc - 24; base = 768 + (u & 1) * 256 + (u >> 1) * 32; }
    BV o;
    #pragma unroll
    for (int e = 0; e < 8; ++e) {
        int kRow = base + quad * 8 + e;
        o.h[e] = (bf16)W[(size_t)kRow * C + n];
    }
    ((bf16x8*)Wt)[t] = o.v;
}

__global__ __launch_bounds__(256, 3)
void fused(const float* __restrict__ x,
           const int* __restrict__ idx1, const int* __restrict__ idx2,
           const int* __restrict__ idx3, const int* __restrict__ idx4,
           const bf16* __restrict__ Wt,
           const float* __restrict__ bias,
           const float* __restrict__ gamma_, const float* __restrict__ beta_,
           float* __restrict__ out)
{
    __shared__ __align__(16) union {
        bf16 a[2][BM * BK];                             // 8192 B, swizzled A tiles
        struct { float rsum[BM][4]; float rsq[BM][4]; float mu[BM]; float rs[BM]; } red;
    } SA;                                               // total LDS = 8192 B
    // NOTE: red (2560 B) lives entirely inside SA.a[0]; the last MFMA (chunk 39,
    // odd) reads SA.a[1] -> no cross-wave epilogue/A-tile overlap hazard.

    const int tid  = threadIdx.x;
    const int lane = tid & 63;
    const int wv   = tid >> 6;       // wave -> column group (wv*64)
    const int quad = lane >> 4;
    const int l16  = lane & 15;
    const int r0   = blockIdx.x * BM;

    const int r_st = tid >> 2;       // staging row 0..63
    const int q_st = tid & 3;        // 8-float eighth of the 32-col slice
    int gr_self = r0 + r_st; if (gr_self >= N_ROWS) gr_self = 0;
    const int ia = idx1[gr_self], ib = idx2[gr_self];
    const int ic = idx3[gr_self], id = idx4[gr_self];
    const float* xself = x + (size_t)gr_self * C + (q_st << 3);

    const int a_w_off = r_st * 32 + ((q_st ^ ((r_st >> 1) & 3)) << 3);
    int a_r_off[4];
    #pragma unroll
    for (int mi = 0; mi < 4; ++mi) {
        int m = mi * 16 + l16;
        a_r_off[mi] = m * 32 + ((quad ^ ((m >> 1) & 3)) << 3);
    }

    // per-lane W fragment pointer: Wq[kc*1024 + ni*64] is this lane's bf16x8
    const bf16x8* Wq = (const bf16x8*)Wt + wv * 256 + lane;

    f32x4 acc[4][4] = {};
    bf16x8 hold;                     // held (a+c)/(b+d) bf16 for odd pair chunk
    bf16x8 wf[4], wfn[4];
    FV2 cur_a, cur_c;                // data for chunk kc+1 (staged this iteration)
    FV2 nxt_a, nxt_c;                // data for chunk kc+2 (issued this iteration)
    int cur_mode, nxt_mode;          // 0 hold/none, 1 self, 2 pair-even

    // ---- prologue: stage chunk 0; prefetch chunk 1 loads; W frags for kc=0
    {
        const float4* p0 = (const float4*)xself;
        float4 s0 = p0[0], s1 = p0[1];                   // chunk 0 (self slice 0)
        const float4* p1 = (const float4*)(xself + 32);  // chunk 1 (self slice 1)
        cur_a.q[0] = p1[0]; cur_a.q[1] = p1[1]; cur_mode = 1;
        #pragma unroll
        for (int j = 0; j < 4; ++j) wf[j] = Wq[j * 64];
        FV2 u; u.q[0] = s0; u.q[1] = s1;
        BV b0;
        #pragma unroll
        for (int j = 0; j < 8; ++j) b0.h[j] = (bf16)u.f[j];
        *(bf16x8*)&SA.a[0][a_w_off] = b0.v;
    }
    LBAR();

    #pragma unroll
    for (int kc = 0; kc < NCHUNK; ++kc) {
        const int kn = kc + 1;
        const int kp = kc + 2;

        // ---- 1. issue loads for chunk kp (two iterations of latency cover)
        nxt_mode = 0;
        if (kp < NCHUNK) {
            if (kp < 8) {
                nxt_mode = 1;
                const float4* p = (const float4*)(xself + (kp << 5));
                nxt_a.q[0] = p[0]; nxt_a.q[1] = p[1];
            } else {
                int u = (kp < 24) ? (kp - 8) : (kp - 24);
                if (!(u & 1)) {
                    nxt_mode = 2;
                    int rA = (kp < 24) ? ia : ib;
                    int rC = (kp < 24) ? ic : id;
                    int off = ((u >> 1) << 5) + (q_st << 3);
                    const float4* pa = (const float4*)(x + (size_t)rA * C + off);
                    const float4* pc = (const float4*)(x + (size_t)rC * C + off);
                    nxt_a.q[0] = pa[0]; nxt_a.q[1] = pa[1];
                    nxt_c.q[0] = pc[0]; nxt_c.q[1] = pc[1];
                }
            }
        }

        // ---- 2. issue W fragment loads for chunk kn (in flight across barrier)
        if (kn < NCHUNK) {
            const bf16x8* wp = Wq + (size_t)kn * CHUNK_V;
            #pragma unroll
            for (int j = 0; j < 4; ++j) wfn[j] = wp[j * 64];
        }

        // ---- 3. stage chunk kn from registers loaded LAST iteration (no vmem wait)
        if (kn < NCHUNK) {
            BV sv;
            if (cur_mode == 1) {
                #pragma unroll
                for (int j = 0; j < 8; ++j) sv.h[j] = (bf16)cur_a.f[j];
            } else if (cur_mode == 2) {
                BV hs;
                #pragma unroll
                for (int j = 0; j < 8; ++j) {
                    sv.h[j] = (bf16)fabsf(cur_a.f[j] - cur_c.f[j]);
                    hs.h[j] = (bf16)(cur_a.f[j] + cur_c.f[j]);
                }
                hold = hs.v;
            } else {
                sv.v = hold;
            }
            *(bf16x8*)&SA.a[kn & 1][a_w_off] = sv.v;
        }

        // ---- 4. MFMA on A buffer kc&1 with in-register W fragments
        {
            const bf16* Ab = SA.a[kc & 1];
            bf16x8 af[4];
            #pragma unroll
            for (int mi = 0; mi < 4; ++mi)
                af[mi] = *(const bf16x8*)&Ab[a_r_off[mi]];
            __builtin_amdgcn_s_setprio(1);
            #pragma unroll
            for (int mi = 0; mi < 4; ++mi)
                #pragma unroll
                for (int ni = 0; ni < 4; ++ni)
                    acc[mi][ni] = __builtin_amdgcn_mfma_f32_16x16x32_bf16(
                        af[mi], wf[ni], acc[mi][ni], 0, 0, 0);
            __builtin_amdgcn_s_setprio(0);
        }

        // ---- 5. rotate register pipelines (renames under full unroll)
        if (kn < NCHUNK) {
            #pragma unroll
            for (int j = 0; j < 4; ++j) wf[j] = wfn[j];
        }
        cur_a = nxt_a; cur_c = nxt_c; cur_mode = nxt_mode;

        // ---- 6. barrier: lgkmcnt(0) only — vmcnt stays counted
        if (kn < NCHUNK) LBAR();
    }

    // ---- epilogue: +bias, LN stats, normalize, residual, exact GELU
    float bcol[4], gcol[4], ecol[4];
    #pragma unroll
    for (int ni = 0; ni < 4; ++ni) {
        int cidx = wv * 64 + ni * 16 + l16;
        bcol[ni] = bias[cidx]; gcol[ni] = gamma_[cidx]; ecol[ni] = beta_[cidx];
    }
    #pragma unroll
    for (int mi = 0; mi < 4; ++mi)
        #pragma unroll
        for (int ni = 0; ni < 4; ++ni)
            #pragma unroll
            for (int rg = 0; rg < 4; ++rg)
                acc[mi][ni][rg] += bcol[ni];

    #pragma unroll
    for (int mi = 0; mi < 4; ++mi) {
        #pragma unroll
        for (int rg = 0; rg < 4; ++rg) {
            float s = 0.f, q = 0.f;
            #pragma unroll
            for (int ni = 0; ni < 4; ++ni) {
                float y = acc[mi][ni][rg];
                s += y; q += y * y;
            }
            #pragma unroll
            for (int m = 1; m <= 8; m <<= 1) {
                s += __shfl_xor(s, m, 64);
                q += __shfl_xor(q, m, 64);
            }
            if (l16 == 0) {
                int row = mi * 16 + quad * 4 + rg;
                SA.red.rsum[row][wv] = s;
                SA.red.rsq [row][wv] = q;
            }
        }
    }
    __syncthreads();
    if (tid < BM) {
        float s  = SA.red.rsum[tid][0] + SA.red.rsum[tid][1] + SA.red.rsum[tid][2] + SA.red.rsum[tid][3];
        float q  = SA.red.rsq [tid][0] + SA.red.rsq [tid][1] + SA.red.rsq [tid][2] + SA.red.rsq [tid][3];
        float mu = s * (1.0f / C);
        float var = q * (1.0f / C) - mu * mu;
        SA.red.mu[tid] = mu;
        SA.red.rs[tid] = rsqrtf(var + LN_EPS);
    }
    __syncthreads();

    #pragma unroll
    for (int mi = 0; mi < 4; ++mi) {
        #pragma unroll
        for (int rg = 0; rg < 4; ++rg) {
            int row  = mi * 16 + quad * 4 + rg;
            int grow = r0 + row;
            if (grow >= N_ROWS) continue;
            float mu = SA.red.mu[row], rs = SA.red.rs[row];
            #pragma unroll
            for (int ni = 0; ni < 4; ++ni) {
                int cidx = wv * 64 + ni * 16 + l16;
                float y = (acc[mi][ni][rg] - mu) * rs * gcol[ni] + ecol[ni];
                y += x[(size_t)grow * C + cidx];
                float g = 0.5f * y * (1.0f + erff(y * 0.70710678118654752f));
                out[(size_t)grow * C + cidx] = g;
            }
        }
    }
}

extern "C" void kernel_launch(void* const* d_in, const int* in_sizes, int n_in,
                              void* d_out, int out_size, void* d_ws, size_t ws_size,
                              hipStream_t stream) {
    const float* x  = (const float*)d_in[0];
    const int*   i1 = (const int*)d_in[1];
    const int*   i2 = (const int*)d_in[2];
    const int*   i3 = (const int*)d_in[3];
    const int*   i4 = (const int*)d_in[4];
    const float* W  = (const float*)d_in[5];
    const float* b  = (const float*)d_in[6];
    const float* gm = (const float*)d_in[7];
    const float* bt = (const float*)d_in[8];
    float* outp = (float*)d_out;
    bf16* Wt = (bf16*)d_ws;   // 40*1024*16 = 640 KB, fragment-order bf16 W

    wprep<<<(NCHUNK * 4 * 4 * 64 + 255) / 256, 256, 0, stream>>>(W, Wt);
    fused<<<(N_ROWS + BM - 1) / BM, 256, 0, stream>>>(
        x, i1, i2, i3, i4, Wt, b, gm, bt, outp);
}